// Round 9
// baseline (368.191 us; speedup 1.0000x reference)
//
#include <hip/hip_runtime.h>

#define BATCH 32
#define TLEN  4096
#define DM    256
#define NS    256
#define BT    (BATCH*TLEN)     // 131072
#define CHL   64               // scan chunk length
#define NCH   (TLEN/CHL)       // 64 chunks

typedef unsigned short u16;
typedef __bf16 bf16x8 __attribute__((ext_vector_type(8)));
typedef float  f32x4  __attribute__((ext_vector_type(4)));

__device__ __forceinline__ u16 f2bf(float f) {
  unsigned u = __builtin_bit_cast(unsigned, f);
  u += 0x7FFFu + ((u >> 16) & 1u);          // RNE
  return (u16)(u >> 16);
}
__device__ __forceinline__ float bf2f(u16 h) {
  unsigned u = ((unsigned)h) << 16;
  return __builtin_bit_cast(float, u);
}
__device__ __forceinline__ float wsum(float v) {
  #pragma unroll
  for (int m = 32; m >= 1; m >>= 1) v += __shfl_xor(v, m, 64);
  return v;
}
__device__ __forceinline__ void gload_lds16(const void* g, void* l) {
  __builtin_amdgcn_global_load_lds(
      (const __attribute__((address_space(1))) void*)(uintptr_t)g,
      (__attribute__((address_space(3))) void*)(unsigned)(uintptr_t)l,
      16, 0, 0);
}
// counted waits + raw barrier (T3/T4): never drain vmcnt to 0 mid-loop
#define VMCNT(N)  asm volatile("s_waitcnt vmcnt(" #N ")" ::: "memory")
#define LGKM0()   asm volatile("s_waitcnt lgkmcnt(0)" ::: "memory")
#define BARRIER() do { __builtin_amdgcn_s_barrier(); asm volatile("" ::: "memory"); } while (0)

// ---------------- prep: weights -> bf16 (gamma folded, -C_im & D folded), lam
__global__ void k_prep(const float* __restrict__ nu_log, const float* __restrict__ th_log,
                       const float* __restrict__ ga_log,
                       const float* __restrict__ B_re, const float* __restrict__ B_im,
                       const float* __restrict__ C_re, const float* __restrict__ C_im,
                       const float* __restrict__ D_mat, const float* __restrict__ mlp_w,
                       float* __restrict__ lam_re, float* __restrict__ lam_im,
                       u16* __restrict__ WB, u16* __restrict__ W2, u16* __restrict__ WM)
{
  const int tid = blockIdx.x * blockDim.x + threadIdx.x;
  const int nt  = gridDim.x * blockDim.x;
  for (int i = tid; i < NS; i += nt) {
    float la = expf(-expf(nu_log[i]));
    float th = expf(th_log[i]);
    lam_re[i] = la * cosf(th);
    lam_im[i] = la * sinf(th);
  }
  // WB: [512][256]  rows 0-255: gamma*B_re, 256-511: gamma*B_im
  for (int i = tid; i < 512 * DM; i += nt) {
    int n = i >> 8, d = i & 255;
    float v = (n < 256) ? B_re[n * DM + d] * expf(ga_log[n])
                        : B_im[(n - 256) * DM + d] * expf(ga_log[n - 256]);
    WB[i] = f2bf(v);
  }
  // W2: [256][768]  k<256: C_re, k<512: -C_im, k>=512: D_mat
  for (int i = tid; i < 256 * 768; i += nt) {
    int n = i / 768, k = i - n * 768;
    float v;
    if (k < 256)      v =  C_re[n * 256 + k];
    else if (k < 512) v = -C_im[n * 256 + (k - 256)];
    else              v =  D_mat[n * 256 + (k - 512)];
    W2[i] = f2bf(v);
  }
  for (int i = tid; i < 256 * 256; i += nt) WM[i] = f2bf(mlp_w[i]);
}

// ---------------- LN1: x -> zskip(bf16), za=leaky (bf16) ---------------------
__global__ __launch_bounds__(256) void k_ln1(const float* __restrict__ x,
                                             const float* __restrict__ g, const float* __restrict__ b,
                                             u16* __restrict__ zskip, u16* __restrict__ za)
{
  const size_t row = (size_t)blockIdx.x * 4 + (threadIdx.x >> 6);
  const int lane = threadIdx.x & 63;
  float4 v = ((const float4*)(x + row * DM))[lane];
  float s = wsum(v.x + v.y + v.z + v.w);
  float q = wsum(v.x * v.x + v.y * v.y + v.z * v.z + v.w * v.w);
  float mean = s * (1.f / DM);
  float rstd = rsqrtf(q * (1.f / DM) - mean * mean + 1e-5f);
  float4 gg = ((const float4*)g)[lane];
  float4 bb = ((const float4*)b)[lane];
  float z0 = (v.x - mean) * rstd * gg.x + bb.x;
  float z1 = (v.y - mean) * rstd * gg.y + bb.y;
  float z2 = (v.z - mean) * rstd * gg.z + bb.z;
  float z3 = (v.w - mean) * rstd * gg.w + bb.w;
  ushort4 zs, zl;
  zs.x = f2bf(z0); zs.y = f2bf(z1); zs.z = f2bf(z2); zs.w = f2bf(z3);
  zl.x = f2bf(z0 >= 0.f ? z0 : 0.01f * z0);
  zl.y = f2bf(z1 >= 0.f ? z1 : 0.01f * z1);
  zl.z = f2bf(z2 >= 0.f ? z2 : 0.01f * z2);
  zl.w = f2bf(z3 >= 0.f ? z3 : 0.01f * z3);
  ((ushort4*)(zskip + row * DM))[lane] = zs;
  ((ushort4*)(za    + row * DM))[lane] = zl;
}

// -- GEMM0: 256x256 tile, 512 thr, 8 waves (4M x 2N), 4-phase, EPI: plain st --
__global__ __launch_bounds__(512, 2) void gemm_u4(
    const u16* __restrict__ A0, const u16* __restrict__ W,
    u16* __restrict__ outb)
{
  __shared__ __align__(16) u16 As[2][256 * 64];   // 64 KB
  __shared__ __align__(16) u16 Bs[2][256 * 64];   // 64 KB
  const int m0 = blockIdx.x * 256;
  const int nw0 = blockIdx.y << 8;
  const int tid = threadIdx.x;
  const int w = tid >> 6, lane = tid & 63;
  const int wr = w >> 1, wc = w & 1;

  f32x4 acc[4][8] = {};

  auto STAGE_A = [&](int p, int k0, int half) {
    #pragma unroll
    for (int j = 0; j < 2; ++j) {
      const int r = half * 16 + w * 2 + j;
      const int row = r * 8 + (lane >> 3);
      const int col = (((lane & 7) ^ (row & 7)) << 3);
      gload_lds16(A0 + (size_t)(m0 + row) * 256 + k0 + col, &As[p][r * 512]);
    }
  };
  auto STAGE_B = [&](int p, int k0, int half) {
    #pragma unroll
    for (int j = 0; j < 2; ++j) {
      const int r = half * 16 + w * 2 + j;
      const int row = r * 8 + (lane >> 3);
      const int col = (((lane & 7) ^ (row & 7)) << 3);
      gload_lds16(W + (size_t)(nw0 + row) * 256 + k0 + col, &Bs[p][r * 512]);
    }
  };

  const int NT = 4;
  STAGE_A(0, 0, 0); STAGE_A(0, 0, 1);
  STAGE_B(0, 0, 0); STAGE_B(0, 0, 1);
  STAGE_A(1, 64, 0); STAGE_A(1, 64, 1); VMCNT(4);
  BARRIER();

  const int lq = (lane >> 4) << 3;

  for (int t = 0; t < NT; ++t) {
    const int p = t & 1;
    const int pn = p ^ 1;
    bf16x8 af[4][2];
    bf16x8 bfr[2][2];

    #pragma unroll
    for (int mi = 0; mi < 4; ++mi) {
      const int ra = wr * 64 + mi * 16 + (lane & 15);
      #pragma unroll
      for (int kki = 0; kki < 2; ++kki) {
        const int koff = kki * 32 + lq;
        af[mi][kki] = *(const bf16x8*)((const char*)&As[p][0] + ra * 128 + ((koff * 2) ^ ((ra & 7) << 4)));
      }
    }
    #pragma unroll
    for (int nn = 0; nn < 2; ++nn) {
      const int rb = wc * 128 + nn * 16 + (lane & 15);
      #pragma unroll
      for (int kki = 0; kki < 2; ++kki) {
        const int koff = kki * 32 + lq;
        bfr[nn][kki] = *(const bf16x8*)((const char*)&Bs[p][0] + rb * 128 + ((koff * 2) ^ ((rb & 7) << 4)));
      }
    }
    if (t + 1 < NT) STAGE_B(pn, (t + 1) << 6, 0);
    BARRIER(); LGKM0();
    __builtin_amdgcn_s_setprio(1);
    #pragma unroll
    for (int kki = 0; kki < 2; ++kki)
      #pragma unroll
      for (int nn = 0; nn < 2; ++nn)
        #pragma unroll
        for (int mi = 0; mi < 4; ++mi)
          acc[mi][nn] = __builtin_amdgcn_mfma_f32_16x16x32_bf16(af[mi][kki], bfr[nn][kki], acc[mi][nn], 0, 0, 0);
    __builtin_amdgcn_s_setprio(0);
    BARRIER();

    #pragma unroll
    for (int q = 1; q < 4; ++q) {
      #pragma unroll
      for (int nn = 0; nn < 2; ++nn) {
        const int rb = wc * 128 + (q * 2 + nn) * 16 + (lane & 15);
        #pragma unroll
        for (int kki = 0; kki < 2; ++kki) {
          const int koff = kki * 32 + lq;
          bfr[nn][kki] = *(const bf16x8*)((const char*)&Bs[p][0] + rb * 128 + ((koff * 2) ^ ((rb & 7) << 4)));
        }
      }
      if (q == 1)      { if (t + 1 < NT) STAGE_B(pn, (t + 1) << 6, 1); }
      else if (q == 2) { if (t + 2 < NT) STAGE_A(p,  (t + 2) << 6, 0); }
      else             { if (t + 2 < NT) STAGE_A(p,  (t + 2) << 6, 1); }
      BARRIER(); LGKM0();
      __builtin_amdgcn_s_setprio(1);
      #pragma unroll
      for (int kki = 0; kki < 2; ++kki)
        #pragma unroll
        for (int nn = 0; nn < 2; ++nn)
          #pragma unroll
          for (int mi = 0; mi < 4; ++mi)
            acc[mi][q * 2 + nn] = __builtin_amdgcn_mfma_f32_16x16x32_bf16(af[mi][kki], bfr[nn][kki], acc[mi][q * 2 + nn], 0, 0, 0);
      __builtin_amdgcn_s_setprio(0);
      if (q == 3) { if (t + 2 < NT) { VMCNT(4); } else { VMCNT(0); } }
      BARRIER();
    }
  }

  const int rq = (lane >> 4) << 2;
  #pragma unroll
  for (int mi = 0; mi < 4; ++mi) {
    #pragma unroll
    for (int rr = 0; rr < 4; ++rr) {
      const int row = wr * 64 + mi * 16 + rq + rr;
      const size_t rbase = (size_t)(m0 + row) * 512 + nw0;
      #pragma unroll
      for (int ni = 0; ni < 8; ++ni) {
        const int col = wc * 128 + ni * 16 + (lane & 15);
        outb[rbase + col] = f2bf(acc[mi][ni][rr]);
      }
    }
  }
}

// -- MEGA: GEMM(K=768) + LN2/leaky -> y' in LDS -> GEMM(y'*WM^T,K=256) + bias
//          + LN3 + zskip -> fp32 out.  256x256 tile, 512 thr, 8 waves 4Mx2N. --
__global__ __launch_bounds__(512, 2) void gemm_mega(
    const u16* __restrict__ A0, int lda0, int ksplit,
    const u16* __restrict__ A1, int lda1,
    int K, const u16* __restrict__ W, int ldw,
    const float* __restrict__ g2, const float* __restrict__ b2,
    const u16* __restrict__ WM, const float* __restrict__ mlp_b,
    const float* __restrict__ g3, const float* __restrict__ b3,
    const u16* __restrict__ zskip, float* __restrict__ outf)
{
  __shared__ __align__(16) u16 SH[4 * 256 * 64];   // 128 KB: As/Bs dbuf, later y'
  const int m0 = blockIdx.x * 256;
  const int tid = threadIdx.x;
  const int w = tid >> 6, lane = tid & 63;
  const int wr = w >> 1, wc = w & 1;           // 4 x 2 waves, wave tile 64 x 128

  f32x4 acc[4][8] = {};

  auto STAGE_A = [&](int p, int k0, int half) {
    const bool second = (k0 >= ksplit);
    const u16* Asrc = second ? A1 : A0;
    const int  alda = second ? lda1 : lda0;
    const int  ak   = second ? (k0 - ksplit) : k0;
    #pragma unroll
    for (int j = 0; j < 2; ++j) {
      const int r = half * 16 + w * 2 + j;
      const int row = r * 8 + (lane >> 3);
      const int col = (((lane & 7) ^ (row & 7)) << 3);
      gload_lds16(Asrc + (size_t)(m0 + row) * alda + ak + col, SH + p * 16384 + r * 512);
    }
  };
  auto STAGE_B = [&](int p, int k0, int half) {
    #pragma unroll
    for (int j = 0; j < 2; ++j) {
      const int r = half * 16 + w * 2 + j;
      const int row = r * 8 + (lane >> 3);
      const int col = (((lane & 7) ^ (row & 7)) << 3);
      gload_lds16(W + (size_t)row * ldw + k0 + col, SH + 32768 + p * 16384 + r * 512);
    }
  };

  const int NT = K >> 6;
  STAGE_A(0, 0, 0); STAGE_A(0, 0, 1);
  STAGE_B(0, 0, 0); STAGE_B(0, 0, 1);
  STAGE_A(1, 64, 0); STAGE_A(1, 64, 1); VMCNT(4);
  BARRIER();

  const int lq = (lane >> 4) << 3;

  for (int t = 0; t < NT; ++t) {
    const int p = t & 1;
    const int pn = p ^ 1;
    const u16* Ab = SH + p * 16384;
    const u16* Bb = SH + 32768 + p * 16384;
    bf16x8 af[4][2];
    bf16x8 bfr[2][2];

    #pragma unroll
    for (int mi = 0; mi < 4; ++mi) {
      const int ra = wr * 64 + mi * 16 + (lane & 15);
      #pragma unroll
      for (int kki = 0; kki < 2; ++kki) {
        const int koff = kki * 32 + lq;
        af[mi][kki] = *(const bf16x8*)((const char*)Ab + ra * 128 + ((koff * 2) ^ ((ra & 7) << 4)));
      }
    }
    #pragma unroll
    for (int nn = 0; nn < 2; ++nn) {
      const int rb = wc * 128 + nn * 16 + (lane & 15);
      #pragma unroll
      for (int kki = 0; kki < 2; ++kki) {
        const int koff = kki * 32 + lq;
        bfr[nn][kki] = *(const bf16x8*)((const char*)Bb + rb * 128 + ((koff * 2) ^ ((rb & 7) << 4)));
      }
    }
    if (t + 1 < NT) STAGE_B(pn, (t + 1) << 6, 0);
    BARRIER(); LGKM0();
    __builtin_amdgcn_s_setprio(1);
    #pragma unroll
    for (int kki = 0; kki < 2; ++kki)
      #pragma unroll
      for (int nn = 0; nn < 2; ++nn)
        #pragma unroll
        for (int mi = 0; mi < 4; ++mi)
          acc[mi][nn] = __builtin_amdgcn_mfma_f32_16x16x32_bf16(af[mi][kki], bfr[nn][kki], acc[mi][nn], 0, 0, 0);
    __builtin_amdgcn_s_setprio(0);
    BARRIER();

    #pragma unroll
    for (int q = 1; q < 4; ++q) {
      #pragma unroll
      for (int nn = 0; nn < 2; ++nn) {
        const int rb = wc * 128 + (q * 2 + nn) * 16 + (lane & 15);
        #pragma unroll
        for (int kki = 0; kki < 2; ++kki) {
          const int koff = kki * 32 + lq;
          bfr[nn][kki] = *(const bf16x8*)((const char*)Bb + rb * 128 + ((koff * 2) ^ ((rb & 7) << 4)));
        }
      }
      if (q == 1)      { if (t + 1 < NT) STAGE_B(pn, (t + 1) << 6, 1); }
      else if (q == 2) { if (t + 2 < NT) STAGE_A(p,  (t + 2) << 6, 0); }
      else             { if (t + 2 < NT) STAGE_A(p,  (t + 2) << 6, 1); }
      BARRIER(); LGKM0();
      __builtin_amdgcn_s_setprio(1);
      #pragma unroll
      for (int kki = 0; kki < 2; ++kki)
        #pragma unroll
        for (int nn = 0; nn < 2; ++nn)
          #pragma unroll
          for (int mi = 0; mi < 4; ++mi)
            acc[mi][q * 2 + nn] = __builtin_amdgcn_mfma_f32_16x16x32_bf16(af[mi][kki], bfr[nn][kki], acc[mi][q * 2 + nn], 0, 0, 0);
      __builtin_amdgcn_s_setprio(0);
      if (q == 3) { if (t + 2 < NT) { VMCNT(4); } else { VMCNT(0); } }
      BARRIER();
    }
  }

  // ---------- LN2 + leaky -> y' into LDS (swizzled) ----------
  const int rq = (lane >> 4) << 2;
  float g8[8], b8[8];
  #pragma unroll
  for (int ni = 0; ni < 8; ++ni) {
    const int col = wc * 128 + ni * 16 + (lane & 15);
    g8[ni] = g2[col]; b8[ni] = b2[col];
  }
  float* red = (float*)SH;                     // [256][4]: (sum,sq) x 2 wc
  #pragma unroll
  for (int mi = 0; mi < 4; ++mi) {
    #pragma unroll
    for (int rr = 0; rr < 4; ++rr) {
      float s = 0.f, q = 0.f;
      #pragma unroll
      for (int ni = 0; ni < 8; ++ni) { float v = acc[mi][ni][rr]; s += v; q += v * v; }
      #pragma unroll
      for (int mm = 1; mm < 16; mm <<= 1) {
        s += __shfl_xor(s, mm, 64);
        q += __shfl_xor(q, mm, 64);
      }
      if ((lane & 15) == 0) {
        const int row = wr * 64 + mi * 16 + rq + rr;
        red[row * 4 + wc * 2]     = s;
        red[row * 4 + wc * 2 + 1] = q;
      }
    }
  }
  __syncthreads();
  float mean2[4][4], rstd2[4][4];
  #pragma unroll
  for (int mi = 0; mi < 4; ++mi) {
    #pragma unroll
    for (int rr = 0; rr < 4; ++rr) {
      const int row = wr * 64 + mi * 16 + rq + rr;
      const f32x4 rv = *(const f32x4*)(red + row * 4);
      const float S = rv[0] + rv[2], Q = rv[1] + rv[3];
      mean2[mi][rr] = S * (1.f / 256.f);
      rstd2[mi][rr] = rsqrtf(Q * (1.f / 256.f) - mean2[mi][rr] * mean2[mi][rr] + 1e-5f);
    }
  }
  __syncthreads();                             // all stat reads done before y' overwrite
  #pragma unroll
  for (int mi = 0; mi < 4; ++mi) {
    #pragma unroll
    for (int rr = 0; rr < 4; ++rr) {
      const int row = wr * 64 + mi * 16 + rq + rr;
      #pragma unroll
      for (int ni = 0; ni < 8; ++ni) {
        const int col = wc * 128 + ni * 16 + (lane & 15);
        float t = (acc[mi][ni][rr] - mean2[mi][rr]) * rstd2[mi][rr] * g8[ni] + b8[ni];
        t = t >= 0.f ? t : 0.01f * t;
        SH[row * 256 + (col ^ ((row & 7) << 3))] = f2bf(t);
      }
    }
  }
  __syncthreads();

  // ---------- second GEMM: o = y' . WM^T  (K=256, B from global/L2) ----------
  f32x4 acc2[4][8] = {};
  #pragma unroll
  for (int s = 0; s < 8; ++s) {
    const int k = s * 32 + lq;
    bf16x8 af2[4], bf2[8];
    #pragma unroll
    for (int mi = 0; mi < 4; ++mi) {
      const int row = wr * 64 + mi * 16 + (lane & 15);
      af2[mi] = *(const bf16x8*)&SH[row * 256 + (k ^ ((row & 7) << 3))];
    }
    #pragma unroll
    for (int ni = 0; ni < 8; ++ni) {
      const int col = wc * 128 + ni * 16 + (lane & 15);
      bf2[ni] = *(const bf16x8*)(WM + (size_t)col * 256 + k);
    }
    #pragma unroll
    for (int ni = 0; ni < 8; ++ni)
      #pragma unroll
      for (int mi = 0; mi < 4; ++mi)
        acc2[mi][ni] = __builtin_amdgcn_mfma_f32_16x16x32_bf16(af2[mi], bf2[ni], acc2[mi][ni], 0, 0, 0);
  }
  __syncthreads();                             // y' reads done before red overwrite

  // ---------- + mlp_b, LN3, + zskip, fp32 out ----------
  float bias8[8], g38[8], b38[8];
  #pragma unroll
  for (int ni = 0; ni < 8; ++ni) {
    const int col = wc * 128 + ni * 16 + (lane & 15);
    bias8[ni] = mlp_b[col]; g38[ni] = g3[col]; b38[ni] = b3[col];
  }
  #pragma unroll
  for (int mi = 0; mi < 4; ++mi) {
    #pragma unroll
    for (int rr = 0; rr < 4; ++rr) {
      float s = 0.f, q = 0.f;
      #pragma unroll
      for (int ni = 0; ni < 8; ++ni) {
        float v = acc2[mi][ni][rr] + bias8[ni];
        s += v; q += v * v;
      }
      #pragma unroll
      for (int mm = 1; mm < 16; mm <<= 1) {
        s += __shfl_xor(s, mm, 64);
        q += __shfl_xor(q, mm, 64);
      }
      if ((lane & 15) == 0) {
        const int row = wr * 64 + mi * 16 + rq + rr;
        red[row * 4 + wc * 2]     = s;
        red[row * 4 + wc * 2 + 1] = q;
      }
    }
  }
  __syncthreads();
  #pragma unroll
  for (int mi = 0; mi < 4; ++mi) {
    #pragma unroll
    for (int rr = 0; rr < 4; ++rr) {
      const int row = wr * 64 + mi * 16 + rq + rr;
      const f32x4 rv = *(const f32x4*)(red + row * 4);
      const float S = rv[0] + rv[2], Q = rv[1] + rv[3];
      const float mean = S * (1.f / 256.f);
      const float rstd = rsqrtf(Q * (1.f / 256.f) - mean * mean + 1e-5f);
      const size_t rbase = (size_t)(m0 + row) * 256;
      #pragma unroll
      for (int ni = 0; ni < 8; ++ni) {
        const int col = wc * 128 + ni * 16 + (lane & 15);
        const float v = acc2[mi][ni][rr] + bias8[ni];
        outf[rbase + col] = (v - mean) * rstd * g38[ni] + b38[ni] + bf2f(zskip[rbase + col]);
      }
    }
  }
}

// ---------------- scan pass A: per-chunk local end-state E and factor A ------
__global__ __launch_bounds__(256) void scan_passA(const u16* __restrict__ u,
    const unsigned char* __restrict__ done,
    const float* __restrict__ lam_re, const float* __restrict__ lam_im,
    float* __restrict__ Ere, float* __restrict__ Eim,
    float* __restrict__ Are, float* __restrict__ Aim)
{
  const int b = blockIdx.x / NCH, c = blockIdx.x % NCH;
  const int n = threadIdx.x;
  const float lr = lam_re[n], li = lam_im[n];
  float hre = 0.f, him = 0.f, pm = 1.f;
  const int t0 = c * CHL;
  for (int t = t0; t < t0 + CHL; ++t) {
    const float m = done[b * TLEN + t] ? 0.f : 1.f;
    pm *= m;
    const float hr = hre * m, hi = him * m;
    const size_t base = ((size_t)(b * TLEN + t)) * 512;
    const float ur = bf2f(u[base + n]), ui = bf2f(u[base + 256 + n]);
    hre = lr * hr - li * hi + ur;
    him = lr * hi + li * hr + ui;
  }
  const size_t idx = ((size_t)(b * NCH + c)) * NS + n;
  Ere[idx] = hre; Eim[idx] = him;
  float pr = lr, pi = li;             // lam^64 via 6 squarings
  #pragma unroll
  for (int s = 0; s < 6; ++s) { float a = pr * pr - pi * pi; float bq = 2.f * pr * pi; pr = a; pi = bq; }
  Are[idx] = pr * pm; Aim[idx] = pi * pm;
}

// ---------------- scan combine: sequential over chunks (tiny) ----------------
__global__ __launch_bounds__(256) void scan_comb(const float* __restrict__ h0re,
    const float* __restrict__ h0im,
    const float* __restrict__ Are, const float* __restrict__ Aim,
    const float* __restrict__ Ere, const float* __restrict__ Eim,
    float* __restrict__ Sre, float* __restrict__ Sim)
{
  const int b = blockIdx.x, n = threadIdx.x;
  float sre = h0re[b * NS + n], sim = h0im[b * NS + n];
  for (int c = 0; c < NCH; ++c) {
    const size_t idx = ((size_t)(b * NCH + c)) * NS + n;
    Sre[idx] = sre; Sim[idx] = sim;
    const float ar = Are[idx], ai = Aim[idx];
    const float nr = ar * sre - ai * sim + Ere[idx];
    const float ni = ar * sim + ai * sre + Eim[idx];
    sre = nr; sim = ni;
  }
}

// ---------------- scan pass C: replay with correct init, write hs in-place ---
__global__ __launch_bounds__(256) void scan_passC(u16* __restrict__ u,
    const unsigned char* __restrict__ done,
    const float* __restrict__ lam_re, const float* __restrict__ lam_im,
    const float* __restrict__ Sre, const float* __restrict__ Sim)
{
  const int b = blockIdx.x / NCH, c = blockIdx.x % NCH;
  const int n = threadIdx.x;
  const float lr = lam_re[n], li = lam_im[n];
  const size_t sidx = ((size_t)(b * NCH + c)) * NS + n;
  float hre = Sre[sidx], him = Sim[sidx];
  const int t0 = c * CHL;
  for (int t = t0; t < t0 + CHL; ++t) {
    const float m = done[b * TLEN + t] ? 0.f : 1.f;
    const float hr = hre * m, hi = him * m;
    const size_t base = ((size_t)(b * TLEN + t)) * 512;
    const float ur = bf2f(u[base + n]), ui = bf2f(u[base + 256 + n]);
    hre = lr * hr - li * hi + ur;
    him = lr * hi + li * hr + ui;
    u[base + n]       = f2bf(hre);    // in-place: row t read above, then overwritten
    u[base + 256 + n] = f2bf(him);
  }
}

extern "C" void kernel_launch(void* const* d_in, const int* in_sizes, int n_in,
                              void* d_out, int out_size, void* d_ws, size_t ws_size,
                              hipStream_t stream)
{
  const float* x      = (const float*)d_in[0];
  const unsigned char* done = (const unsigned char*)d_in[1];
  const float* h0re   = (const float*)d_in[2];
  const float* h0im   = (const float*)d_in[3];
  const float* nu_log = (const float*)d_in[4];
  const float* th_log = (const float*)d_in[5];
  const float* ga_log = (const float*)d_in[6];
  const float* B_re   = (const float*)d_in[7];
  const float* B_im   = (const float*)d_in[8];
  const float* C_re   = (const float*)d_in[9];
  const float* C_im   = (const float*)d_in[10];
  const float* D_mat  = (const float*)d_in[11];
  const float* mlp_w  = (const float*)d_in[12];
  const float* mlp_b  = (const float*)d_in[13];
  const float* ln1_g  = (const float*)d_in[14];
  const float* ln1_b  = (const float*)d_in[15];
  const float* ln2_g  = (const float*)d_in[16];
  const float* ln2_b  = (const float*)d_in[17];
  const float* ln3_g  = (const float*)d_in[18];
  const float* ln3_b  = (const float*)d_in[19];
  (void)in_sizes; (void)n_in; (void)out_size; (void)ws_size;

  char* ws = (char*)d_ws;
  float* lam_re = (float*)(ws + 0);
  float* lam_im = (float*)(ws + 1024);
  u16* WB = (u16*)(ws + 4096);                           // [512][256]  256 KB
  u16* W2 = (u16*)(ws + 4096 + 512 * 256 * 2);           // [256][768]  384 KB
  u16* WM = (u16*)(ws + 4096 + 512 * 256 * 2 + 256 * 768 * 2); // [256][256] 128 KB

  size_t off = (size_t)1 << 20;
  u16* zskip = (u16*)(ws + off); off += (size_t)BT * DM * 2;   // 67 MB
  u16* za    = (u16*)(ws + off); off += (size_t)BT * DM * 2;   // 67 MB
  u16* ubuf  = (u16*)(ws + off); off += (size_t)BT * 512 * 2;  // 134 MB (u -> hs in place)
  float* Ere = (float*)(ws + off); off += (size_t)BATCH * NCH * NS * 4;
  float* Eim = (float*)(ws + off); off += (size_t)BATCH * NCH * NS * 4;
  float* Are = (float*)(ws + off); off += (size_t)BATCH * NCH * NS * 4;
  float* Aim = (float*)(ws + off); off += (size_t)BATCH * NCH * NS * 4;
  float* Sre = (float*)(ws + off); off += (size_t)BATCH * NCH * NS * 4;
  float* Sim = (float*)(ws + off); off += (size_t)BATCH * NCH * NS * 4;

  // 0) pack weights (bf16), lam
  k_prep<<<256, 256, 0, stream>>>(nu_log, th_log, ga_log, B_re, B_im, C_re, C_im,
                                  D_mat, mlp_w, lam_re, lam_im, WB, W2, WM);
  // 1) LN1 -> zskip, za=leaky(z)
  k_ln1<<<BT / 4, 256, 0, stream>>>(x, ln1_g, ln1_b, zskip, za);
  // 2) u_re|u_im -> ubuf (packed [BT][512]): 4-phase GEMM, y-block = re/im half
  gemm_u4<<<dim3(BT / 256, 2), 512, 0, stream>>>(za, WB, ubuf);
  // 3-5) chunked parallel scan (in-place ubuf -> hs)
  scan_passA<<<BATCH * NCH, 256, 0, stream>>>(ubuf, done, lam_re, lam_im, Ere, Eim, Are, Aim);
  scan_comb <<<BATCH,       256, 0, stream>>>(h0re, h0im, Are, Aim, Ere, Eim, Sre, Sim);
  scan_passC<<<BATCH * NCH, 256, 0, stream>>>(ubuf, done, lam_re, lam_im, Sre, Sim);
  // 6+7 fused) y' = leaky(LN2([hs|z].W2^T)); out = LN3(y'.WM^T + mlp_b) + zskip
  gemm_mega<<<BT / 256, 512, 0, stream>>>(ubuf, 512, 512, za, 256,
                                          768, W2, 768, ln2_g, ln2_b,
                                          WM, mlp_b, ln3_g, ln3_b,
                                          zskip, (float*)d_out);
}

// Round 10
// 330.433 us; speedup vs baseline: 1.1143x; 1.1143x over previous
//
#include <hip/hip_runtime.h>

#define BATCH 32
#define TLEN  4096
#define DM    256
#define NS    256
#define BT    (BATCH*TLEN)     // 131072
#define CHL   64               // scan chunk length
#define NCH   (TLEN/CHL)       // 64 chunks

typedef unsigned short u16;
typedef __bf16 bf16x8 __attribute__((ext_vector_type(8)));
typedef float  f32x4  __attribute__((ext_vector_type(4)));

__device__ __forceinline__ u16 f2bf(float f) {
  unsigned u = __builtin_bit_cast(unsigned, f);
  u += 0x7FFFu + ((u >> 16) & 1u);          // RNE
  return (u16)(u >> 16);
}
__device__ __forceinline__ float bf2f(u16 h) {
  unsigned u = ((unsigned)h) << 16;
  return __builtin_bit_cast(float, u);
}
__device__ __forceinline__ float wsum(float v) {
  #pragma unroll
  for (int m = 32; m >= 1; m >>= 1) v += __shfl_xor(v, m, 64);
  return v;
}
__device__ __forceinline__ void gload_lds16(const void* g, void* l) {
  __builtin_amdgcn_global_load_lds(
      (const __attribute__((address_space(1))) void*)(uintptr_t)g,
      (__attribute__((address_space(3))) void*)(unsigned)(uintptr_t)l,
      16, 0, 0);
}
// counted waits + raw barrier (T3/T4): never drain vmcnt to 0 mid-loop
#define VMCNT(N)  asm volatile("s_waitcnt vmcnt(" #N ")" ::: "memory")
#define LGKM0()   asm volatile("s_waitcnt lgkmcnt(0)" ::: "memory")
#define BARRIER() do { __builtin_amdgcn_s_barrier(); asm volatile("" ::: "memory"); } while (0)

// ---------------- prep: weights -> bf16 (gamma folded, -C_im & D folded), lam
__global__ void k_prep(const float* __restrict__ nu_log, const float* __restrict__ th_log,
                       const float* __restrict__ ga_log,
                       const float* __restrict__ B_re, const float* __restrict__ B_im,
                       const float* __restrict__ C_re, const float* __restrict__ C_im,
                       const float* __restrict__ D_mat, const float* __restrict__ mlp_w,
                       float* __restrict__ lam_re, float* __restrict__ lam_im,
                       u16* __restrict__ WB, u16* __restrict__ W2, u16* __restrict__ WM)
{
  const int tid = blockIdx.x * blockDim.x + threadIdx.x;
  const int nt  = gridDim.x * blockDim.x;
  for (int i = tid; i < NS; i += nt) {
    float la = expf(-expf(nu_log[i]));
    float th = expf(th_log[i]);
    lam_re[i] = la * cosf(th);
    lam_im[i] = la * sinf(th);
  }
  // WB: [512][256]  rows 0-255: gamma*B_re, 256-511: gamma*B_im
  for (int i = tid; i < 512 * DM; i += nt) {
    int n = i >> 8, d = i & 255;
    float v = (n < 256) ? B_re[n * DM + d] * expf(ga_log[n])
                        : B_im[(n - 256) * DM + d] * expf(ga_log[n - 256]);
    WB[i] = f2bf(v);
  }
  // W2: [256][768]  k<256: C_re, k<512: -C_im, k>=512: D_mat
  for (int i = tid; i < 256 * 768; i += nt) {
    int n = i / 768, k = i - n * 768;
    float v;
    if (k < 256)      v =  C_re[n * 256 + k];
    else if (k < 512) v = -C_im[n * 256 + (k - 256)];
    else              v =  D_mat[n * 256 + (k - 512)];
    W2[i] = f2bf(v);
  }
  for (int i = tid; i < 256 * 256; i += nt) WM[i] = f2bf(mlp_w[i]);
}

// ---------------- LN1: x -> za = leaky(LN1(x)) (bf16). skip recovered later --
__global__ __launch_bounds__(256) void k_ln1(const float* __restrict__ x,
                                             const float* __restrict__ g, const float* __restrict__ b,
                                             u16* __restrict__ za)
{
  const size_t row = (size_t)blockIdx.x * 4 + (threadIdx.x >> 6);
  const int lane = threadIdx.x & 63;
  float4 v = ((const float4*)(x + row * DM))[lane];
  float s = wsum(v.x + v.y + v.z + v.w);
  float q = wsum(v.x * v.x + v.y * v.y + v.z * v.z + v.w * v.w);
  float mean = s * (1.f / DM);
  float rstd = rsqrtf(q * (1.f / DM) - mean * mean + 1e-5f);
  float4 gg = ((const float4*)g)[lane];
  float4 bb = ((const float4*)b)[lane];
  float z0 = (v.x - mean) * rstd * gg.x + bb.x;
  float z1 = (v.y - mean) * rstd * gg.y + bb.y;
  float z2 = (v.z - mean) * rstd * gg.z + bb.z;
  float z3 = (v.w - mean) * rstd * gg.w + bb.w;
  ushort4 zl;
  zl.x = f2bf(z0 >= 0.f ? z0 : 0.01f * z0);
  zl.y = f2bf(z1 >= 0.f ? z1 : 0.01f * z1);
  zl.z = f2bf(z2 >= 0.f ? z2 : 0.01f * z2);
  zl.w = f2bf(z3 >= 0.f ? z3 : 0.01f * z3);
  ((ushort4*)(za + row * DM))[lane] = zl;
}

// -- unified 4-phase GEMM: 256x256 tile, 512 thr, 8 waves (4M x 2N) -----------
// per phase {ds_read subtile, stage one half-tile, barrier, lgkmcnt(0),
// 16 MFMA, barrier}; vmcnt counted once per K-tile.
// EPI 0: out = acc (bf16), stride ldo. 1024 blocks XCD-paired: both N-halves
//        of one m-tile land on the same XCD (shared A-panel L2 reuse).
// EPI 1: y' = leaky(LN(acc; g,b)) -> bf16 outb (stride 256)
// EPI 2: out = LN(acc + bias; g,b) + inv_leaky(zsrc) -> fp32 outf (stride 256)
template <int EPI>
__global__ __launch_bounds__(512, 2) void gemm_fused(
    const u16* __restrict__ A0, int lda0, int ksplit,
    const u16* __restrict__ A1, int lda1,
    int K, const u16* __restrict__ W, int ldw,
    const float* __restrict__ g, const float* __restrict__ b,
    const float* __restrict__ bias, const u16* __restrict__ zsrc,
    u16* __restrict__ outb, float* __restrict__ outf, int ldo)
{
  __shared__ __align__(16) u16 As[2][256 * 64];   // 64 KB
  __shared__ __align__(16) u16 Bs[2][256 * 64];   // 64 KB
  int mt, nw0;
  if constexpr (EPI == 0) {
    // 1024 blocks: xcd = bid&7 owns m-tiles [xcd*64, xcd*64+64), both y-halves
    const int bid = blockIdx.x;
    const int xcd = bid & 7, s = bid >> 3;
    mt  = xcd * 64 + (s >> 1);
    nw0 = (s & 1) << 8;
  } else { mt = blockIdx.x; nw0 = 0; }
  const int m0 = mt * 256;
  const int tid = threadIdx.x;
  const int w = tid >> 6, lane = tid & 63;
  const int wr = w >> 1, wc = w & 1;           // 4 x 2 waves, wave tile 64 x 128

  f32x4 acc[4][8] = {};

  // one half-tile = 128 rows x 64 cols = 16 KB = 512 thr x 16 B x 2 rounds
  auto STAGE_A = [&](int p, int k0, int half) {
    const bool second = (k0 >= ksplit);
    const u16* Asrc = second ? A1 : A0;
    const int  alda = second ? lda1 : lda0;
    const int  ak   = second ? (k0 - ksplit) : k0;
    #pragma unroll
    for (int j = 0; j < 2; ++j) {
      const int r = half * 16 + w * 2 + j;     // 0..31
      const int row = r * 8 + (lane >> 3);     // 0..255
      const int col = (((lane & 7) ^ (row & 7)) << 3);
      gload_lds16(Asrc + (size_t)(m0 + row) * alda + ak + col, &As[p][r * 512]);
    }
  };
  auto STAGE_B = [&](int p, int k0, int half) {
    #pragma unroll
    for (int j = 0; j < 2; ++j) {
      const int r = half * 16 + w * 2 + j;
      const int row = r * 8 + (lane >> 3);
      const int col = (((lane & 7) ^ (row & 7)) << 3);
      gload_lds16(W + (size_t)(nw0 + row) * ldw + k0 + col, &Bs[p][r * 512]);
    }
  };

  const int NT = K >> 6;
  // prologue: A(0), B(0) full; A(1) full. vmcnt(4) leaves A(1) in flight.
  STAGE_A(0, 0, 0); STAGE_A(0, 0, 1);
  STAGE_B(0, 0, 0); STAGE_B(0, 0, 1);
  if (NT > 1) { STAGE_A(1, 64, 0); STAGE_A(1, 64, 1); VMCNT(4); }
  else        { VMCNT(0); }
  BARRIER();

  const int lq = (lane >> 4) << 3;

  for (int t = 0; t < NT; ++t) {
    const int p = t & 1;
    const int pn = p ^ 1;
    bf16x8 af[4][2];
    bf16x8 bfr[2][2];

    // ---- phase 0: af (8 reads) + bfr ni{0,1} (4 reads); stage B-lo(t+1) ----
    #pragma unroll
    for (int mi = 0; mi < 4; ++mi) {
      const int ra = wr * 64 + mi * 16 + (lane & 15);
      #pragma unroll
      for (int kki = 0; kki < 2; ++kki) {
        const int koff = kki * 32 + lq;
        af[mi][kki] = *(const bf16x8*)((const char*)&As[p][0] + ra * 128 + ((koff * 2) ^ ((ra & 7) << 4)));
      }
    }
    #pragma unroll
    for (int nn = 0; nn < 2; ++nn) {
      const int rb = wc * 128 + nn * 16 + (lane & 15);
      #pragma unroll
      for (int kki = 0; kki < 2; ++kki) {
        const int koff = kki * 32 + lq;
        bfr[nn][kki] = *(const bf16x8*)((const char*)&Bs[p][0] + rb * 128 + ((koff * 2) ^ ((rb & 7) << 4)));
      }
    }
    if (t + 1 < NT) STAGE_B(pn, (t + 1) << 6, 0);
    BARRIER(); LGKM0();
    __builtin_amdgcn_s_setprio(1);
    #pragma unroll
    for (int kki = 0; kki < 2; ++kki)
      #pragma unroll
      for (int nn = 0; nn < 2; ++nn)
        #pragma unroll
        for (int mi = 0; mi < 4; ++mi)
          acc[mi][nn] = __builtin_amdgcn_mfma_f32_16x16x32_bf16(af[mi][kki], bfr[nn][kki], acc[mi][nn], 0, 0, 0);
    __builtin_amdgcn_s_setprio(0);
    BARRIER();

    // ---- phases 1..3: bfr pair (4 reads); stage B-hi(t+1)/A-lo(t+2)/A-hi(t+2)
    #pragma unroll
    for (int q = 1; q < 4; ++q) {
      #pragma unroll
      for (int nn = 0; nn < 2; ++nn) {
        const int rb = wc * 128 + (q * 2 + nn) * 16 + (lane & 15);
        #pragma unroll
        for (int kki = 0; kki < 2; ++kki) {
          const int koff = kki * 32 + lq;
          bfr[nn][kki] = *(const bf16x8*)((const char*)&Bs[p][0] + rb * 128 + ((koff * 2) ^ ((rb & 7) << 4)));
        }
      }
      if (q == 1)      { if (t + 1 < NT) STAGE_B(pn, (t + 1) << 6, 1); }
      else if (q == 2) { if (t + 2 < NT) STAGE_A(p,  (t + 2) << 6, 0); }
      else             { if (t + 2 < NT) STAGE_A(p,  (t + 2) << 6, 1); }
      BARRIER(); LGKM0();
      __builtin_amdgcn_s_setprio(1);
      #pragma unroll
      for (int kki = 0; kki < 2; ++kki)
        #pragma unroll
        for (int nn = 0; nn < 2; ++nn)
          #pragma unroll
          for (int mi = 0; mi < 4; ++mi)
            acc[mi][q * 2 + nn] = __builtin_amdgcn_mfma_f32_16x16x32_bf16(af[mi][kki], bfr[nn][kki], acc[mi][q * 2 + nn], 0, 0, 0);
      __builtin_amdgcn_s_setprio(0);
      if (q == 3) { if (t + 2 < NT) { VMCNT(4); } else { VMCNT(0); } }
      BARRIER();
    }
  }

  const int rq = (lane >> 4) << 2;             // row quad base within 16

  // ---- EPI 0: plain bf16 store at stride ldo, col offset nw0 ----
  if constexpr (EPI == 0) {
    #pragma unroll
    for (int mi = 0; mi < 4; ++mi) {
      #pragma unroll
      for (int rr = 0; rr < 4; ++rr) {
        const int row = wr * 64 + mi * 16 + rq + rr;
        const size_t rbase = (size_t)(m0 + row) * ldo + nw0;
        #pragma unroll
        for (int ni = 0; ni < 8; ++ni) {
          const int col = wc * 128 + ni * 16 + (lane & 15);
          outb[rbase + col] = f2bf(acc[mi][ni][rr]);
        }
      }
    }
    return;
  }

  // ---- fused LayerNorm epilogue (wave tile 64 x 128) ----
  float g8[8], b8[8], bias8[8];
  #pragma unroll
  for (int ni = 0; ni < 8; ++ni) {
    const int col = wc * 128 + ni * 16 + (lane & 15);
    g8[ni] = g[col]; b8[ni] = b[col];
    if constexpr (EPI == 2) bias8[ni] = bias[col];
  }

  float* red = (float*)&As[0][0];              // [256][4]: (sum,sq) x 2 wc
  #pragma unroll
  for (int mi = 0; mi < 4; ++mi) {
    #pragma unroll
    for (int rr = 0; rr < 4; ++rr) {
      float s = 0.f, q = 0.f;
      #pragma unroll
      for (int ni = 0; ni < 8; ++ni) {
        float v = acc[mi][ni][rr];
        if constexpr (EPI == 2) v += bias8[ni];
        s += v; q += v * v;
      }
      #pragma unroll
      for (int mm = 1; mm < 16; mm <<= 1) {
        s += __shfl_xor(s, mm, 64);
        q += __shfl_xor(q, mm, 64);
      }
      if ((lane & 15) == 0) {
        const int row = wr * 64 + mi * 16 + rq + rr;
        red[row * 4 + wc * 2]     = s;
        red[row * 4 + wc * 2 + 1] = q;
      }
    }
  }
  __syncthreads();

  #pragma unroll
  for (int mi = 0; mi < 4; ++mi) {
    #pragma unroll
    for (int rr = 0; rr < 4; ++rr) {
      const int row = wr * 64 + mi * 16 + rq + rr;
      const float S = red[row * 4] + red[row * 4 + 2];
      const float Q = red[row * 4 + 1] + red[row * 4 + 3];
      const float mean = S * (1.f / 256.f);
      const float rstd = rsqrtf(Q * (1.f / 256.f) - mean * mean + 1e-5f);
      const size_t rbase = (size_t)(m0 + row) * 256;
      #pragma unroll
      for (int ni = 0; ni < 8; ++ni) {
        const int col = wc * 128 + ni * 16 + (lane & 15);
        float v = acc[mi][ni][rr];
        if constexpr (EPI == 2) v += bias8[ni];
        float t = (v - mean) * rstd * g8[ni] + b8[ni];
        if constexpr (EPI == 1) {
          t = t >= 0.f ? t : 0.01f * t;
          outb[rbase + col] = f2bf(t);
        } else {
          float zv = bf2f(zsrc[rbase + col]);          // za = leaky(z)
          zv = zv >= 0.f ? zv : 100.f * zv;            // invert leaky -> z
          outf[rbase + col] = t + zv;
        }
      }
    }
  }
}

// ---------------- scan pass A: per-chunk local end-state E and factor A ------
__global__ __launch_bounds__(256) void scan_passA(const u16* __restrict__ u,
    const unsigned char* __restrict__ done,
    const float* __restrict__ lam_re, const float* __restrict__ lam_im,
    float* __restrict__ Ere, float* __restrict__ Eim,
    float* __restrict__ Are, float* __restrict__ Aim)
{
  const int b = blockIdx.x / NCH, c = blockIdx.x % NCH;
  const int n = threadIdx.x;
  const float lr = lam_re[n], li = lam_im[n];
  float hre = 0.f, him = 0.f, pm = 1.f;
  const int t0 = c * CHL;
  for (int t = t0; t < t0 + CHL; ++t) {
    const float m = done[b * TLEN + t] ? 0.f : 1.f;
    pm *= m;
    const float hr = hre * m, hi = him * m;
    const size_t base = ((size_t)(b * TLEN + t)) * 512;
    const float ur = bf2f(u[base + n]), ui = bf2f(u[base + 256 + n]);
    hre = lr * hr - li * hi + ur;
    him = lr * hi + li * hr + ui;
  }
  const size_t idx = ((size_t)(b * NCH + c)) * NS + n;
  Ere[idx] = hre; Eim[idx] = him;
  float pr = lr, pi = li;             // lam^64 via 6 squarings
  #pragma unroll
  for (int s = 0; s < 6; ++s) { float a = pr * pr - pi * pi; float bq = 2.f * pr * pi; pr = a; pi = bq; }
  Are[idx] = pr * pm; Aim[idx] = pi * pm;
}

// ---------------- scan combine: sequential over chunks (tiny) ----------------
__global__ __launch_bounds__(256) void scan_comb(const float* __restrict__ h0re,
    const float* __restrict__ h0im,
    const float* __restrict__ Are, const float* __restrict__ Aim,
    const float* __restrict__ Ere, const float* __restrict__ Eim,
    float* __restrict__ Sre, float* __restrict__ Sim)
{
  const int b = blockIdx.x, n = threadIdx.x;
  float sre = h0re[b * NS + n], sim = h0im[b * NS + n];
  for (int c = 0; c < NCH; ++c) {
    const size_t idx = ((size_t)(b * NCH + c)) * NS + n;
    Sre[idx] = sre; Sim[idx] = sim;
    const float ar = Are[idx], ai = Aim[idx];
    const float nr = ar * sre - ai * sim + Ere[idx];
    const float ni = ar * sim + ai * sre + Eim[idx];
    sre = nr; sim = ni;
  }
}

// ---------------- scan pass C: replay with correct init, write hs in-place ---
__global__ __launch_bounds__(256) void scan_passC(u16* __restrict__ u,
    const unsigned char* __restrict__ done,
    const float* __restrict__ lam_re, const float* __restrict__ lam_im,
    const float* __restrict__ Sre, const float* __restrict__ Sim)
{
  const int b = blockIdx.x / NCH, c = blockIdx.x % NCH;
  const int n = threadIdx.x;
  const float lr = lam_re[n], li = lam_im[n];
  const size_t sidx = ((size_t)(b * NCH + c)) * NS + n;
  float hre = Sre[sidx], him = Sim[sidx];
  const int t0 = c * CHL;
  for (int t = t0; t < t0 + CHL; ++t) {
    const float m = done[b * TLEN + t] ? 0.f : 1.f;
    const float hr = hre * m, hi = him * m;
    const size_t base = ((size_t)(b * TLEN + t)) * 512;
    const float ur = bf2f(u[base + n]), ui = bf2f(u[base + 256 + n]);
    hre = lr * hr - li * hi + ur;
    him = lr * hi + li * hr + ui;
    u[base + n]       = f2bf(hre);    // in-place: row t read above, then overwritten
    u[base + 256 + n] = f2bf(him);
  }
}

extern "C" void kernel_launch(void* const* d_in, const int* in_sizes, int n_in,
                              void* d_out, int out_size, void* d_ws, size_t ws_size,
                              hipStream_t stream)
{
  const float* x      = (const float*)d_in[0];
  const unsigned char* done = (const unsigned char*)d_in[1];
  const float* h0re   = (const float*)d_in[2];
  const float* h0im   = (const float*)d_in[3];
  const float* nu_log = (const float*)d_in[4];
  const float* th_log = (const float*)d_in[5];
  const float* ga_log = (const float*)d_in[6];
  const float* B_re   = (const float*)d_in[7];
  const float* B_im   = (const float*)d_in[8];
  const float* C_re   = (const float*)d_in[9];
  const float* C_im   = (const float*)d_in[10];
  const float* D_mat  = (const float*)d_in[11];
  const float* mlp_w  = (const float*)d_in[12];
  const float* mlp_b  = (const float*)d_in[13];
  const float* ln1_g  = (const float*)d_in[14];
  const float* ln1_b  = (const float*)d_in[15];
  const float* ln2_g  = (const float*)d_in[16];
  const float* ln2_b  = (const float*)d_in[17];
  const float* ln3_g  = (const float*)d_in[18];
  const float* ln3_b  = (const float*)d_in[19];
  (void)in_sizes; (void)n_in; (void)out_size; (void)ws_size;

  char* ws = (char*)d_ws;
  float* lam_re = (float*)(ws + 0);
  float* lam_im = (float*)(ws + 1024);
  u16* WB = (u16*)(ws + 4096);                           // [512][256]  256 KB
  u16* W2 = (u16*)(ws + 4096 + 512 * 256 * 2);           // [256][768]  384 KB
  u16* WM = (u16*)(ws + 4096 + 512 * 256 * 2 + 256 * 768 * 2); // [256][256] 128 KB

  size_t off = (size_t)1 << 20;
  u16* za    = (u16*)(ws + off); off += (size_t)BT * DM * 2;   // 67 MB
  u16* ubuf  = (u16*)(ws + off); off += (size_t)BT * 512 * 2;  // 134 MB (u -> hs in place)
  u16* ybuf  = (u16*)(ws + off); off += (size_t)BT * NS * 2;   // 67 MB
  float* Ere = (float*)(ws + off); off += (size_t)BATCH * NCH * NS * 4;
  float* Eim = (float*)(ws + off); off += (size_t)BATCH * NCH * NS * 4;
  float* Are = (float*)(ws + off); off += (size_t)BATCH * NCH * NS * 4;
  float* Aim = (float*)(ws + off); off += (size_t)BATCH * NCH * NS * 4;
  float* Sre = (float*)(ws + off); off += (size_t)BATCH * NCH * NS * 4;
  float* Sim = (float*)(ws + off); off += (size_t)BATCH * NCH * NS * 4;

  // 0) pack weights (bf16), lam
  k_prep<<<256, 256, 0, stream>>>(nu_log, th_log, ga_log, B_re, B_im, C_re, C_im,
                                  D_mat, mlp_w, lam_re, lam_im, WB, W2, WM);
  // 1) LN1 -> za = leaky(z) only (skip recovered by inverse-leaky in EPI 2)
  k_ln1<<<BT / 4, 256, 0, stream>>>(x, ln1_g, ln1_b, za);
  // 2) u_re|u_im -> ubuf (packed [BT][512]): 4-phase GEMM, XCD-paired grid
  gemm_fused<0><<<1024, 512, 0, stream>>>(za, 256, 1 << 28, nullptr, 0,
                                          256, WB, 256, nullptr, nullptr,
                                          nullptr, nullptr, ubuf, nullptr, 512);
  // 3-5) chunked parallel scan (in-place ubuf -> hs)
  scan_passA<<<BATCH * NCH, 256, 0, stream>>>(ubuf, done, lam_re, lam_im, Ere, Eim, Are, Aim);
  scan_comb <<<BATCH,       256, 0, stream>>>(h0re, h0im, Are, Aim, Ere, Eim, Sre, Sim);
  scan_passC<<<BATCH * NCH, 256, 0, stream>>>(ubuf, done, lam_re, lam_im, Sre, Sim);
  // 6) y' = leaky(LN2( [hs | z] . W2^T ))   (K = 512 + 256)
  gemm_fused<1><<<BT / 256, 512, 0, stream>>>(ubuf, 512, 512, za, 256,
                                              768, W2, 768, ln2_g, ln2_b,
                                              nullptr, nullptr, ybuf, nullptr, 256);
  // 7) out = LN3( y' . WM^T + mlp_b ) + inv_leaky(za)   (fp32)
  gemm_fused<2><<<BT / 256, 512, 0, stream>>>(ybuf, 256, 256, ybuf, 256,
                                              256, WM, 256, ln3_g, ln3_b,
                                              mlp_b, za, nullptr, (float*)d_out, 256);
}